// Round 8
// baseline (427.036 us; speedup 1.0000x reference)
//
#include <hip/hip_runtime.h>
#include <math.h>

#define NCLS 20
#define IGNORE_IDX 255
#define LOG2E 1.4426950408889634f
#define NTHR 256
#define TILE 256   // voxels per tile (1 per thread)
#define RING 3     // LDS tile ring depth
#define NBLK 512   // 2 blocks/CU
#define NSLOT 32   // global partial-sum slots

__device__ __forceinline__ float wave_reduce(float v) {
#pragma unroll
  for (int off = 32; off > 0; off >>= 1) v += __shfl_xor(v, off, 64);
  return v;
}

__device__ __forceinline__ float neg_log_clamped(float x, bool cond) {
  if (!cond) return 0.0f;
  float xs = fmaxf(x, 1e-38f);
  return fminf(-logf(xs), 100.0f);
}

// Fire-and-forget global->LDS: 64 lanes x 16B = 1KB/instr, no dest VGPRs.
// LDS dest = wave-uniform base + lane*16 (HW); global src is per-lane.
__device__ __forceinline__ void gload_lds16(const float* g, float* l) {
  __builtin_amdgcn_global_load_lds(
      (const __attribute__((address_space(1))) void*)g,
      (__attribute__((address_space(3))) void*)l, 16, 0, 0);
}

// Layout of s_acc rows / ws columns: [0..19] sum_p, [20..39] nominator,
// [40..59] ct_count, [60..63] unused.
//
// r8 design notes — store-like reads:
//  - r0-r7: every VGPR-dest load kernel plateaus at 5-11 GB/s/CU across
//    occupancies 23-63%. The harness fillBuffer (8 VGPR, 9.5% occ) does
//    26 GB/s/CU: writes are fire-and-forget. The cap is the VGPR-load
//    retire path. global_load_lds is the read-side analog (no dest regs).
//  - r5 failed because __syncthreads() forces vmcnt(0) before s_barrier
//    (guide "5: structural) -> 1-deep serial. Fix = T3/T4: RAW s_barrier +
//    hand-counted vmcnt, never drained to 0 in the loop.
//  - Ring of 3 x 20KB tiles; tiles t..t+2 in flight = 18 vm-ops/wave;
//    s_waitcnt vmcnt(12) retires exactly tile t. ~96KB outstanding/CU
//    vs ~14KB Little's-law need at 6 TB/s.
//  - Buffer safety: stage(t+2) (into buf (t+2)%3 = (t-1)%3) is issued only
//    after the compute-done barrier of t-1; all ds_read values of a tile
//    are consumed (compiler-waited) before that barrier.
//  - Compute: double LDS read, NO per-class register arrays (no AGPR bait);
//    per-class sums via fire-and-forget ds_add into s_acc[c][tid&31]
//    (2-way same-bank = free, measured 0 conflicts r0-r7).
__global__ __launch_bounds__(NTHR) void pass1(const float* __restrict__ pred,
                                              const int* __restrict__ target,
                                              float* __restrict__ ws, int N,
                                              int T) {
  __shared__ float s_x[RING][NCLS][TILE];  // 61.44 KB
  __shared__ float s_acc[3 * NCLS][32];    // 7.68 KB
  const int tid = threadIdx.x;
  const int wid = tid >> 6;
  const int lane = tid & 63;
  const int sl = tid & 31;

  {
    float* p = &s_acc[0][0];
    for (int i = tid; i < 3 * NCLS * 32; i += NTHR) p[i] = 0.0f;
  }
  __syncthreads();

  const long long base = (long long)blockIdx.x * T * TILE;

  // stage tile tt (block-local): 5 classes per wave, clamped src, linear dest
#define STAGE(tt)                                                         \
  do {                                                                    \
    long long voff = base + (long long)(tt)*TILE + lane * 4;              \
    if (voff > (long long)N - 4) voff = (long long)N - 4;                 \
    const int o = (int)voff;                                              \
    _Pragma("unroll") for (int i = 0; i < 5; ++i) {                       \
      const int c = wid * 5 + i;                                          \
      gload_lds16(pred + (size_t)c * N + o, &s_x[(tt) % RING][c][0]);     \
    }                                                                     \
  } while (0)

#define TGT(tt, dst)                                                      \
  do {                                                                    \
    long long nn = base + (long long)(tt)*TILE + tid;                     \
    if (nn > (long long)N - 1) nn = (long long)N - 1;                     \
    dst = target[nn];                                                     \
  } while (0)

  // prologue: tiles 0 and 1 in flight (order: tgt before stage per tile)
  int t_n1 = IGNORE_IDX, t_n2 = IGNORE_IDX;
  TGT(0, t_n1);
  STAGE(0);
  if (T > 1) {
    TGT(1, t_n2);
    STAGE(1);
  }

  for (int it = 0; it < T; ++it) {
    const int t_cur = t_n1;
    t_n1 = t_n2;
    const int remt = T - 1 - it;
    if (remt >= 2) {  // issue tile it+2 (buf (it-1)%RING, safe post-barrier)
      TGT(it + 2, t_n2);
      STAGE(it + 2);
    }
    // counted wait: retire exactly tile it's 6 ops; keep 12 (or 6) in flight
    if (remt >= 2)
      asm volatile("s_waitcnt vmcnt(12)" ::: "memory");
    else if (remt == 1)
      asm volatile("s_waitcnt vmcnt(6)" ::: "memory");
    else
      asm volatile("s_waitcnt vmcnt(0)" ::: "memory");
    __builtin_amdgcn_s_barrier();        // data-ready (raw: no vmcnt drain)
    __builtin_amdgcn_sched_barrier(0);   // rule #18: no hoist across wait

    // ---- compute tile it: 1 voxel/thread, double LDS read, all transient
    {
      const float* sx = &s_x[it % RING][0][0];
      const long long n = base + (long long)it * TILE + tid;
      const bool in = (n < N);
      float Z = 0.0f, pt = 0.0f;
#pragma unroll
      for (int c = 0; c < NCLS; ++c) {
        const float e =
            __builtin_amdgcn_exp2f(fminf(sx[c * TILE + tid], 80.0f) * LOG2E);
        Z += e;
        pt = (c == t_cur) ? e : pt;
      }
      const bool msk = in && (t_cur != IGNORE_IDX);
      const float w = msk ? __builtin_amdgcn_rcpf(Z) : 0.0f;
      if (msk) {
        atomicAdd(&s_acc[NCLS + t_cur][sl], pt * w);    // nominator
        atomicAdd(&s_acc[2 * NCLS + t_cur][sl], 1.0f);  // ct_count
      }
#pragma unroll
      for (int c = 0; c < NCLS; ++c) {
        const float e =
            __builtin_amdgcn_exp2f(fminf(sx[c * TILE + tid], 80.0f) * LOG2E);
        atomicAdd(&s_acc[c][sl], e * w);  // w==0 for invalid -> adds 0
      }
    }
    __builtin_amdgcn_s_barrier();  // compute-done: buf (it)%RING reusable
  }
  __syncthreads();  // drains lgkm (ds atomics) + final sync

  // block flush: 60 rows x 32 slots, rotated start -> distinct banks/lane.
  if (tid < 3 * NCLS) {
    const float* row = s_acc[tid];
    float v = 0.0f;
#pragma unroll
    for (int i = 0; i < 32; ++i) v += row[(i + tid) & 31];
    // relaxed global atomics; pass2 is a separate dispatch (kernel boundary
    // provides visibility). 32 slots -> chains of NBLK/32 per address.
    atomicAdd(&ws[(size_t)(blockIdx.x & (NSLOT - 1)) * 64 + tid], v);
  }
#undef STAGE
#undef TGT
}

__global__ __launch_bounds__(64) void pass2(const float* __restrict__ ws,
                                            float* __restrict__ out) {
  __shared__ float s[64];
  const int lane = threadIdx.x;
  float a = 0.0f;
#pragma unroll
  for (int r = 0; r < NSLOT; ++r) a += ws[r * 64 + lane];  // 32 indep loads

  // n_masked = sum of ct_count columns (lanes 40..59), uniform collective
  const float n_masked =
      wave_reduce((lane >= 2 * NCLS && lane < 3 * NCLS) ? a : 0.0f);

  // LDS bounce for per-class gather — NO divergent cross-lane ops
  s[lane] = a;
  __syncthreads();

  float loss = 0.0f, validf = 0.0f;
  if (lane < NCLS) {
    const float sump = s[lane];
    const float nom = s[NCLS + lane];
    const float cnt = s[2 * NCLS + lane];
    const bool valid = cnt > 0.0f;
    const float prec = nom / fmaxf(sump, 1e-38f);
    const float rec = nom / fmaxf(cnt, 1.0f);
    const float negc = n_masked - cnt;
    const float specn = n_masked - sump - cnt + nom;
    const float spec = specn / fmaxf(negc, 1.0f);
    loss = neg_log_clamped(prec, valid && (sump > 0.0f)) +
           neg_log_clamped(rec, valid) +
           neg_log_clamped(spec, valid && (negc > 0.0f));
    validf = valid ? 1.0f : 0.0f;
  }
  loss = wave_reduce(loss);      // uniform: all 64 lanes participate
  validf = wave_reduce(validf);
  if (lane == 0) out[0] = loss / validf;
}

extern "C" void kernel_launch(void* const* d_in, const int* in_sizes, int n_in,
                              void* d_out, int out_size, void* d_ws, size_t ws_size,
                              hipStream_t stream) {
  const float* pred = (const float*)d_in[0];
  const int* target = (const int*)d_in[1];
  const int N = in_sizes[1];  // voxel count; C = in_sizes[0]/N = 20
  const int ntile = (N + TILE - 1) / TILE;  // 8192 for N = 2^21
  const int T = (ntile + NBLK - 1) / NBLK;  // 16 tiles per block

  hipMemsetAsync(d_ws, 0, NSLOT * 64 * sizeof(float), stream);
  pass1<<<NBLK, NTHR, 0, stream>>>(pred, target, (float*)d_ws, N, T);
  pass2<<<1, 64, 0, stream>>>((const float*)d_ws, (float*)d_out);
}